// Round 11
// baseline (365.765 us; speedup 1.0000x reference)
//
#include <hip/hip_runtime.h>
#include <math.h>

// Problem constants: B=2, H=240, W=1216, ITER=3, NUM=9, CH=27
#define B_ 2
#define H_ 240
#define W_ 1216
#define CH_ 27
#define NUM_ 9
#define PIX_ (B_ * H_ * W_)   // 583680
#define CHL 40                // LDS channel stride (16B-aligned chunks)
#define TX 32
#define TY 8
#define HALO_W (TX + 2)       // 34
#define HALO_H (TY + 2)       // 10
#define G_ELEMS (CH_ * HALO_H * HALO_W)   // 9180 guide elements per tile
// cur-window for LDS gathers: [tileY0-8 .. tileY0+16] x [tileX0-8 .. tileX0+40]
#define GH 8                  // gather halo
#define HS_W (TX + 2 * GH + 1)   // 49
#define HS_H (TY + 2 * GH + 1)   // 25
#define SC_ELEMS (HS_H * HS_W)           // 1225 floats

typedef __attribute__((ext_vector_type(8))) __bf16 bf16x8;
typedef __attribute__((ext_vector_type(16))) float f32x16;

// ---------------------------------------------------------------------------
// Pre-kernel: swizzle conv_w into MFMA fragment lane order.
// wlin[iter][tap][ks][lane(64)][8] bf16 (linear i = tap*2+ks within an iter).
// Fragment layout (A- and B-role identical for 32x32x16): lane&31 = non-K index
// (= oc), k = (lane>>5)*8 + j; ic = ks*16 + k.
// oc map: n<18 -> iter*18+n (offsets), 18<=n<27 -> 54+iter*9+(n-18) (aff).
// ---------------------------------------------------------------------------
__global__ __launch_bounds__(256) void prep_weights(
    const float* __restrict__ conv_w, __bf16* __restrict__ wlin)
{
    int idx = blockIdx.x * 256 + threadIdx.x;
    if (idx >= 3 * 9 * 2 * 64) return;
    int lane = idx & 63;
    int grp = idx >> 6;         // (iter*9+tap)*2 + ks
    int ks = grp & 1;
    int tapi = (grp >> 1) % 9;
    int it = (grp >> 1) / 9;
    int n = lane & 31;
    int half = lane >> 5;
    __align__(16) __bf16 v8[8];
    #pragma unroll
    for (int j = 0; j < 8; ++j) {
        int ic = ks * 16 + half * 8 + j;
        float v = 0.f;
        if (ic < CH_ && n < CH_) {
            int oc = (n < 18) ? (it * 18 + n) : (54 + it * NUM_ + (n - 18));
            v = conv_w[(size_t)(oc * CH_ + ic) * 9 + tapi];
        }
        v8[j] = (__bf16)v;
    }
    *(bf16x8*)(wlin + (size_t)idx * 8) = *(const bf16x8*)v8;
}

// ---------------------------------------------------------------------------
// Fused per-iteration kernel v8 = v7 with the gt workspace detour DELETED:
// each iter stages raw fp32 guide (pristine input -> full-rate reads; L3-hot
// after iter 0) directly into the bf16 LDS tile using batched-issue staging:
//   phase 1: 36 unconditional clamped guide loads/thread issued back-to-back
//            (cndmask-zero for OOB, no branches) + 5 cur loads + 18 wlin
//            B-fragments — one latency drain for everything;
//   phase 2: LDS writes (bf16 convert) + zero-fill ch 27..31 + barrier;
//   phase 3: MFMA (swapped operands, D[oc][px]) + in-wave channel exchange;
//   phase 4: softmax + LDS-windowed bilinear gather + blend (v5/v7-proven).
// ---------------------------------------------------------------------------
__global__ __launch_bounds__(256, 3) void dyspn_iter_v8(
    const float* __restrict__ guide, const __bf16* __restrict__ wlin,
    const float* __restrict__ conv_b, const float* __restrict__ tap,
    const float* __restrict__ confidence, const float* __restrict__ sp_dep,
    const float* __restrict__ cur_in, float* __restrict__ out_cur,
    float* __restrict__ pred, float* __restrict__ feat,
    const float* __restrict__ input, int iter)
{
    __shared__ __align__(16) __bf16 sG[HALO_H * HALO_W * CHL];  // 27200 B
    __shared__ float sCur[HS_H * HS_W];                          // 4900 B

    const int tid = threadIdx.x;
    const int lane = tid & 63;
    const int w = tid >> 6;          // wave id 0..3 -> output rows 2w, 2w+1
    const int xl = lane & 31;
    const int half = lane >> 5;
    const int tileX0 = blockIdx.x * TX;
    const int tileY0 = blockIdx.y * TY;
    const int b = blockIdx.z;
    const size_t bbase = (size_t)b * (H_ * W_);
    const float* cur = cur_in + bbase;
    const float* gb  = guide + (size_t)b * CH_ * H_ * W_;

    // ---- phase 1a: issue guide tile loads (static 36-deep unroll) ----
    float gval[36];
    #pragma unroll
    for (int k = 0; k < 36; ++k) {
        int idx = tid + k * 256;
        int i2 = (idx < G_ELEMS) ? idx : (G_ELEMS - 1);
        int ic  = i2 / (HALO_H * HALO_W);
        int rem = i2 - ic * (HALO_H * HALO_W);
        int row = rem / HALO_W;
        int px  = rem - row * HALO_W;
        int gy = tileY0 + row - 1;
        int gx = tileX0 + px - 1;
        bool ok = (gx >= 0) && (gx < W_) && (gy >= 0) && (gy < H_);
        int cy = min(max(gy, 0), H_ - 1);
        int cx = min(max(gx, 0), W_ - 1);
        float v = gb[((size_t)ic * H_ + cy) * W_ + cx];
        gval[k] = ok ? v : 0.f;
    }

    // ---- phase 1b: issue cur-window loads (static 5-deep unroll) ----
    const int winX0 = tileX0 - GH;
    const int winY0 = tileY0 - GH;
    float cv[5];
    #pragma unroll
    for (int k = 0; k < 5; ++k) {
        int idx = tid + k * 256;
        float v = 0.f;
        if (idx < SC_ELEMS) {
            int r = idx / HS_W;
            int cpos = idx - r * HS_W;
            int gy = winY0 + r;
            int gx = winX0 + cpos;
            if (gx >= 0 && gx < W_ && gy >= 0 && gy < H_)
                v = cur[(size_t)gy * W_ + gx];
        }
        cv[k] = v;
    }

    // ---- phase 1c: issue ALL 18 B-fragment loads ----
    bf16x8 Bf[18];
    #pragma unroll
    for (int i = 0; i < 18; ++i)
        Bf[i] = *(const bf16x8*)(wlin + ((size_t)(iter * 18 + i) * 64 + lane) * 8);

    // ---- phase 2: LDS writes (bf16 convert), zero-fill pad, barrier ----
    #pragma unroll
    for (int k = 0; k < 36; ++k) {
        int idx = tid + k * 256;
        if (idx < G_ELEMS) {
            int ic  = idx / (HALO_H * HALO_W);
            int rem = idx - ic * (HALO_H * HALO_W);
            sG[rem * CHL + ic] = (__bf16)gval[k];
        }
    }
    // channels 27..31 read by MFMA fragments -> zero them (5 per pixel)
    for (int idx = tid; idx < HALO_H * HALO_W * 5; idx += 256) {
        int rem = idx / 5;
        int ic  = CH_ + (idx - rem * 5);
        sG[rem * CHL + ic] = (__bf16)0.f;
    }
    #pragma unroll
    for (int k = 0; k < 5; ++k) {
        int idx = tid + k * 256;
        if (idx < SC_ELEMS) sCur[idx] = cv[k];
    }
    __syncthreads();

    // ---- phase 3: MFMA ----
    f32x16 acc0 = {0,0,0,0,0,0,0,0,0,0,0,0,0,0,0,0};
    f32x16 acc1 = {0,0,0,0,0,0,0,0,0,0,0,0,0,0,0,0};

    #pragma unroll
    for (int ks = 0; ks < 2; ++ks) {
        #pragma unroll
        for (int kw = 0; kw < 3; ++kw) {
            bf16x8 A4[4];
            #pragma unroll
            for (int d = 0; d < 4; ++d) {
                const __bf16* ap = sG + (size_t)((2 * w + d) * HALO_W + xl + kw) * CHL
                                 + ks * 16 + half * 8;
                A4[d] = *(const bf16x8*)ap;
            }
            #pragma unroll
            for (int kh = 0; kh < 3; ++kh) {
                int t = kh * 3 + kw;
                // swapped operands: D[oc][px]; acc0 = output row 2w, acc1 = 2w+1
                acc0 = __builtin_amdgcn_mfma_f32_32x32x16_bf16(Bf[t * 2 + ks], A4[kh],     acc0, 0, 0, 0);
                acc1 = __builtin_amdgcn_mfma_f32_32x32x16_bf16(Bf[t * 2 + ks], A4[kh + 1], acc1, 0, 0, 0);
            }
        }
    }

    // ---- in-wave channel completion ----
    // D layout 32x32: col = lane&31 = pixel x, row(oc) = (r&3)+8*(r>>2)+4*(lane>>5).
    float oth[16];
    #pragma unroll
    for (int r = 0; r < 16; ++r) {
        float send = half ? acc0[r] : acc1[r];
        oth[r] = __shfl_xor(send, 32, 64);
    }

    float v27[CH_];
    #pragma unroll
    for (int c = 0; c < CH_; ++c) {
        int r = (c & 3) + 4 * (c >> 3);
        int hc = (c >> 2) & 1;
        float own = half ? acc1[r] : acc0[r];
        float val = (hc == half) ? own : oth[r];
        int oc = (c < 18) ? (iter * 18 + c) : (54 + iter * NUM_ + (c - 18));
        v27[c] = val + conv_b[oc];     // wave-uniform -> scalar load
    }

    // ---- softmax over aff channels 18..26 ----
    float m = v27[18];
    #pragma unroll
    for (int n = 1; n < 9; ++n) m = fmaxf(m, v27[18 + n]);
    float a[9]; float s = 0.f;
    #pragma unroll
    for (int n = 0; n < 9; ++n) { a[n] = __expf(v27[18 + n] - m); s += a[n]; }
    const float inv_s = 1.f / s;

    // ---- 9-tap bilinear propagation (LDS window, global fallback) ----
    const int x = tileX0 + xl;
    const int y = tileY0 + 2 * w + half;
    float agg = 0.f;
    #pragma unroll
    for (int n = 0; n < 9; ++n) {
        float px = v27[2 * n]     + tap[2 * n]     + (float)x;
        float py = v27[2 * n + 1] + tap[2 * n + 1] + (float)y;
        float x0f = floorf(px), y0f = floorf(py);
        float wx = px - x0f, wy = py - y0f;
        int x0 = (int)x0f, y0 = (int)y0f;
        int lx = x0 - winX0, ly = y0 - winY0;
        float v00, v01, v10, v11;
        if ((unsigned)lx <= (unsigned)(HS_W - 2) && (unsigned)ly <= (unsigned)(HS_H - 2)) {
            int li = ly * HS_W + lx;
            v00 = sCur[li];
            v01 = sCur[li + 1];
            v10 = sCur[li + HS_W];
            v11 = sCur[li + HS_W + 1];
        } else {
            bool vx0 = (x0 >= 0) && (x0 < W_);
            bool vx1 = (x0 + 1 >= 0) && (x0 + 1 < W_);
            bool vy0 = (y0 >= 0) && (y0 < H_);
            bool vy1 = (y0 + 1 >= 0) && (y0 + 1 < H_);
            int cx0 = min(max(x0, 0), W_ - 1), cx1 = min(max(x0 + 1, 0), W_ - 1);
            int cy0 = min(max(y0, 0), H_ - 1), cy1 = min(max(y0 + 1, 0), H_ - 1);
            v00 = 0.f; v01 = 0.f; v10 = 0.f; v11 = 0.f;
            if (vy0) {
                const float* row = cur + (size_t)cy0 * W_;
                if (vx0) v00 = row[cx0];
                if (vx1) v01 = row[cx1];
            }
            if (vy1) {
                const float* row = cur + (size_t)cy1 * W_;
                if (vx0) v10 = row[cx0];
                if (vx1) v11 = row[cx1];
            }
        }
        float val = (1.f - wy) * ((1.f - wx) * v00 + wx * v01)
                  +        wy  * ((1.f - wx) * v10 + wx * v11);
        agg = fmaf(val, a[n] * inv_s, agg);
    }

    const int pix = b * (H_ * W_) + y * W_ + x;
    float c  = confidence[pix];
    float sp = sp_dep[pix];
    float sgn = (sp > 0.f) ? 1.f : ((sp < 0.f) ? -1.f : 0.f);
    float conf = sgn / (1.f + __expf(-c));
    float nc = (1.f - conf) * agg + conf * sp;

    out_cur[pix] = nc;
    if (pred) pred[pix] = nc;
    if (feat) feat[pix] = input[pix];
}

// ---------------------------------------------------------------------------
// Fallback (fp32 direct) if workspace is too small
// ---------------------------------------------------------------------------
__global__ __launch_bounds__(256) void dyspn_iter_fp32(
    const float* __restrict__ guide, const float* __restrict__ conv_w,
    const float* __restrict__ conv_b, const float* __restrict__ tap,
    const float* __restrict__ confidence, const float* __restrict__ sp_dep,
    const float* __restrict__ cur_in, float* __restrict__ out_cur,
    float* __restrict__ pred, float* __restrict__ feat,
    const float* __restrict__ input, int iter)
{
    __shared__ float sg[CH_ * HALO_H * HALO_W];
    const int tid = threadIdx.x;
    const int tileX0 = blockIdx.x * TX;
    const int tileY0 = blockIdx.y * TY;
    const int b = blockIdx.z;
    for (int idx = tid; idx < CH_ * HALO_H * HALO_W; idx += 256) {
        int ic  = idx / (HALO_H * HALO_W);
        int rem = idx % (HALO_H * HALO_W);
        int ly = rem / HALO_W;
        int lx = rem % HALO_W;
        int gy = tileY0 + ly - 1;
        int gx = tileX0 + lx - 1;
        float v = 0.f;
        if (gx >= 0 && gx < W_ && gy >= 0 && gy < H_)
            v = guide[((b * CH_ + ic) * H_ + gy) * W_ + gx];
        sg[idx] = v;
    }
    __syncthreads();
    const int tx = tid % TX;
    const int ty = tid / TX;
    const int x = tileX0 + tx;
    const int y = tileY0 + ty;
    const int oc0 = iter * 18;
    const int oc1 = 54 + iter * NUM_;
    float acc[27];
    #pragma unroll
    for (int j = 0; j < 18; ++j) acc[j] = conv_b[oc0 + j];
    #pragma unroll
    for (int j = 0; j < 9; ++j)  acc[18 + j] = conv_b[oc1 + j];
    for (int ic = 0; ic < CH_; ++ic) {
        float g[9];
        #pragma unroll
        for (int t = 0; t < 9; ++t) {
            int dy = t / 3, dx = t % 3;
            g[t] = sg[ic * (HALO_H * HALO_W) + (ty + dy) * HALO_W + (tx + dx)];
        }
        #pragma unroll
        for (int j = 0; j < 18; ++j) {
            const float* wp = conv_w + ((oc0 + j) * CH_ + ic) * 9;
            #pragma unroll
            for (int t = 0; t < 9; ++t) acc[j] = fmaf(wp[t], g[t], acc[j]);
        }
        #pragma unroll
        for (int j = 0; j < 9; ++j) {
            const float* wp = conv_w + ((oc1 + j) * CH_ + ic) * 9;
            #pragma unroll
            for (int t = 0; t < 9; ++t) acc[18 + j] = fmaf(wp[t], g[t], acc[18 + j]);
        }
    }
    float m = acc[18];
    #pragma unroll
    for (int n = 1; n < 9; ++n) m = fmaxf(m, acc[18 + n]);
    float a[9]; float s = 0.f;
    #pragma unroll
    for (int n = 0; n < 9; ++n) { a[n] = __expf(acc[18 + n] - m); s += a[n]; }
    const float inv_s = 1.f / s;
    const float* cur = cur_in + b * (H_ * W_);
    float agg = 0.f;
    #pragma unroll
    for (int n = 0; n < 9; ++n) {
        float px = acc[2 * n]     + tap[2 * n]     + (float)x;
        float py = acc[2 * n + 1] + tap[2 * n + 1] + (float)y;
        float x0f = floorf(px), y0f = floorf(py);
        float wx = px - x0f, wy = py - y0f;
        int x0 = (int)x0f, y0 = (int)y0f;
        bool vx0 = (x0 >= 0) && (x0 < W_);
        bool vx1 = (x0 + 1 >= 0) && (x0 + 1 < W_);
        bool vy0 = (y0 >= 0) && (y0 < H_);
        bool vy1 = (y0 + 1 >= 0) && (y0 + 1 < H_);
        int cx0 = min(max(x0, 0), W_ - 1), cx1 = min(max(x0 + 1, 0), W_ - 1);
        int cy0 = min(max(y0, 0), H_ - 1), cy1 = min(max(y0 + 1, 0), H_ - 1);
        float v00 = 0.f, v01 = 0.f, v10 = 0.f, v11 = 0.f;
        if (vy0) {
            const float* row = cur + cy0 * W_;
            if (vx0) v00 = row[cx0];
            if (vx1) v01 = row[cx1];
        }
        if (vy1) {
            const float* row = cur + cy1 * W_;
            if (vx0) v10 = row[cx0];
            if (vx1) v11 = row[cx1];
        }
        float val = (1.f - wy) * ((1.f - wx) * v00 + wx * v01)
                  +        wy  * ((1.f - wx) * v10 + wx * v11);
        agg = fmaf(val, a[n] * inv_s, agg);
    }
    const int pix = b * (H_ * W_) + y * W_ + x;
    float c  = confidence[pix];
    float sp = sp_dep[pix];
    float sgn = (sp > 0.f) ? 1.f : ((sp < 0.f) ? -1.f : 0.f);
    float conf = sgn / (1.f + __expf(-c));
    float nc = (1.f - conf) * agg + conf * sp;
    out_cur[pix] = nc;
    if (pred) pred[pix] = nc;
    if (feat) feat[pix] = input[pix];
}

extern "C" void kernel_launch(void* const* d_in, const int* in_sizes, int n_in,
                              void* d_out, int out_size, void* d_ws, size_t ws_size,
                              hipStream_t stream) {
    (void)in_sizes; (void)n_in; (void)out_size;
    const float* input      = (const float*)d_in[0];
    const float* guide      = (const float*)d_in[1];
    const float* sp_dep     = (const float*)d_in[2];
    const float* confidence = (const float*)d_in[3];
    const float* conv_w     = (const float*)d_in[4];
    const float* conv_b     = (const float*)d_in[5];
    const float* tap        = (const float*)d_in[6];

    float* out   = (float*)d_out;
    const int P  = PIX_;
    float* pred  = out;
    float* feat  = out + P;
    float* inter = out + 2 * P;

    dim3 grid(W_ / TX, H_ / TY, B_);  // 38 x 30 x 2
    dim3 block(256);

    const size_t wlin_bytes = (size_t)3 * 9 * 2 * 64 * 8 * 2;  // 55,296

    if (ws_size >= wlin_bytes) {
        __bf16* wlin = (__bf16*)d_ws;

        prep_weights<<<(3 * 9 * 2 * 64 + 255) / 256, 256, 0, stream>>>(conv_w, wlin);

        for (int i = 0; i < 3; ++i) {
            const float* cur = (i == 0) ? input : (inter + (i - 1) * P);
            dyspn_iter_v8<<<grid, block, 0, stream>>>(
                guide, wlin, conv_b, tap, confidence, sp_dep,
                cur, inter + i * P,
                (i == 2) ? pred : nullptr,
                (i == 0) ? feat : nullptr,
                input, i);
        }
    } else {
        for (int i = 0; i < 3; ++i) {
            const float* cur = (i == 0) ? input : (inter + (i - 1) * P);
            dyspn_iter_fp32<<<grid, block, 0, stream>>>(
                guide, conv_w, conv_b, tap, confidence, sp_dep,
                cur, inter + i * P,
                (i == 2) ? pred : nullptr,
                (i == 0) ? feat : nullptr,
                input, i);
        }
    }
}

// Round 12
// 185.006 us; speedup vs baseline: 1.9770x; 1.9770x over previous
//
#include <hip/hip_runtime.h>
#include <math.h>

// Problem constants: B=2, H=240, W=1216, ITER=3, NUM=9, CH=27
#define B_ 2
#define H_ 240
#define W_ 1216
#define CH_ 27
#define NUM_ 9
#define PIX_ (B_ * H_ * W_)   // 583680
#define CHP 32                // channel pad for gt layout (64 B/pixel)
#define CHL 40                // LDS channel stride (16B-aligned chunks)
#define TX 32
#define TY 8
#define HALO_W (TX + 2)       // 34
#define HALO_H (TY + 2)       // 10
// cur-window for LDS gathers: [tileY0-8 .. tileY0+16] x [tileX0-8 .. tileX0+40]
#define GH 8                  // gather halo
#define HS_W (TX + 2 * GH + 1)   // 49
#define HS_H (TY + 2 * GH + 1)   // 25
#define GT_ELEMS (HALO_H * HALO_W * 4)   // 1360 uint4 chunks
#define SC_ELEMS (HS_H * HS_W)           // 1225 floats
#define GX_ (W_ / TX)         // 38 tiles in x
#define GY_ (H_ / TY)         // 30 tiles in y
#define NBLK (GX_ * GY_ * B_) // 2280 blocks = 8 * 285 (exactly divisible -> bijective swizzle)

typedef __attribute__((ext_vector_type(8))) __bf16 bf16x8;
typedef __attribute__((ext_vector_type(16))) float f32x16;

// ---------------------------------------------------------------------------
// Pre-kernel 1: transpose guide [B,27,H,W] fp32 -> gt [B*H*W][32] bf16.
// Plain coalesced uint4 stores; ~16 µs = BW roofline for its 100 MB.
// ---------------------------------------------------------------------------
__global__ __launch_bounds__(256) void transpose_guide(
    const float* __restrict__ guide, __bf16* __restrict__ gt)
{
    int pix = blockIdx.x * 256 + threadIdx.x;
    if (pix >= PIX_) return;
    int b = pix / (H_ * W_);
    int off = pix - b * (H_ * W_);   // y*W + x
    __align__(16) __bf16 tmp[CHP];
    const float* src = guide + (size_t)b * CH_ * H_ * W_ + off;
    #pragma unroll
    for (int ic = 0; ic < CH_; ++ic)
        tmp[ic] = (__bf16)src[(size_t)ic * (H_ * W_)];
    #pragma unroll
    for (int ic = CH_; ic < CHP; ++ic) tmp[ic] = (__bf16)0.f;
    bf16x8* dst = (bf16x8*)(gt + (size_t)pix * CHP);
    const bf16x8* s8 = (const bf16x8*)tmp;
    #pragma unroll
    for (int c = 0; c < 4; ++c) dst[c] = s8[c];
}

// ---------------------------------------------------------------------------
// Pre-kernel 2: swizzle conv_w into MFMA fragment lane order.
// wlin[iter][tap][ks][lane(64)][8] bf16 (linear i = tap*2+ks within an iter).
// Fragment layout (A- and B-role identical for 32x32x16): lane&31 = non-K index
// (= oc), k = (lane>>5)*8 + j; ic = ks*16 + k.
// oc map: n<18 -> iter*18+n (offsets), 18<=n<27 -> 54+iter*9+(n-18) (aff).
// ---------------------------------------------------------------------------
__global__ __launch_bounds__(256) void prep_weights(
    const float* __restrict__ conv_w, __bf16* __restrict__ wlin)
{
    int idx = blockIdx.x * 256 + threadIdx.x;
    if (idx >= 3 * 9 * 2 * 64) return;
    int lane = idx & 63;
    int grp = idx >> 6;         // (iter*9+tap)*2 + ks
    int ks = grp & 1;
    int tapi = (grp >> 1) % 9;
    int it = (grp >> 1) / 9;
    int n = lane & 31;
    int half = lane >> 5;
    __align__(16) __bf16 v8[8];
    #pragma unroll
    for (int j = 0; j < 8; ++j) {
        int ic = ks * 16 + half * 8 + j;
        float v = 0.f;
        if (ic < CH_ && n < CH_) {
            int oc = (n < 18) ? (it * 18 + n) : (54 + it * NUM_ + (n - 18));
            v = conv_w[(size_t)(oc * CH_ + ic) * 9 + tapi];
        }
        v8[j] = (__bf16)v;
    }
    *(bf16x8*)(wlin + (size_t)idx * 8) = *(const bf16x8*)v8;
}

// ---------------------------------------------------------------------------
// Fused per-iteration kernel v9 = v7 (batched-issue staging, swapped-operand
// MFMA, in-wave channel exchange, LDS-windowed gather) + XCD-aware block
// swizzle (T1): 1D grid of 2280 blocks, bijectively remapped so each XCD
// owns a contiguous row-major chunk of tiles -> gt/cur halo lines are
// same-L2 re-reads instead of 8-XCD scatter.
// ---------------------------------------------------------------------------
__global__ __launch_bounds__(256, 3) void dyspn_iter_v9(
    const __bf16* __restrict__ gt, const __bf16* __restrict__ wlin,
    const float* __restrict__ conv_b, const float* __restrict__ tap,
    const float* __restrict__ confidence, const float* __restrict__ sp_dep,
    const float* __restrict__ cur_in, float* __restrict__ out_cur,
    float* __restrict__ pred, float* __restrict__ feat,
    const float* __restrict__ input, int iter)
{
    __shared__ __align__(16) __bf16 sG[HALO_H * HALO_W * CHL];  // 27200 B
    __shared__ float sCur[HS_H * HS_W];                          // 4900 B

    const int tid = threadIdx.x;
    const int lane = tid & 63;
    const int w = tid >> 6;          // wave id 0..3 -> output rows 2w, 2w+1
    const int xl = lane & 31;
    const int half = lane >> 5;

    // XCD-aware bijective swizzle: hardware round-robins blockIdx.x % 8 across
    // XCDs; give each XCD a contiguous logical chunk (2280 = 8 * 285 exactly).
    const int bid = blockIdx.x;
    const int swz = (bid & 7) * (NBLK / 8) + (bid >> 3);
    const int b   = swz / (GX_ * GY_);
    const int rem = swz - b * (GX_ * GY_);
    const int tileY0 = (rem / GX_) * TY;
    const int tileX0 = (rem - (rem / GX_) * GX_) * TX;

    const size_t bbase = (size_t)b * (H_ * W_);
    const float* cur = cur_in + bbase;

    // ---- phase 1a: issue gt tile loads (static 6-deep unroll) ----
    uint4 gv[6];
    #pragma unroll
    for (int k = 0; k < 6; ++k) {
        int idx = tid + k * 256;
        uint4 v = make_uint4(0, 0, 0, 0);
        if (idx < GT_ELEMS) {
            int chunk = idx & 3;
            int p = idx >> 2;               // 0..339
            int row = p / HALO_W;
            int px = p - row * HALO_W;
            int gy = tileY0 + row - 1;
            int gx = tileX0 + px - 1;
            if (gx >= 0 && gx < W_ && gy >= 0 && gy < H_) {
                size_t pg = bbase + (size_t)gy * W_ + gx;
                v = ((const uint4*)(gt + pg * CHP))[chunk];
            }
        }
        gv[k] = v;
    }

    // ---- phase 1b: issue cur-window loads (static 5-deep unroll) ----
    const int winX0 = tileX0 - GH;
    const int winY0 = tileY0 - GH;
    float cv[5];
    #pragma unroll
    for (int k = 0; k < 5; ++k) {
        int idx = tid + k * 256;
        float v = 0.f;
        if (idx < SC_ELEMS) {
            int r = idx / HS_W;
            int cpos = idx - r * HS_W;
            int gy = winY0 + r;
            int gx = winX0 + cpos;
            if (gx >= 0 && gx < W_ && gy >= 0 && gy < H_)
                v = cur[(size_t)gy * W_ + gx];
        }
        cv[k] = v;
    }

    // ---- phase 1c: issue ALL 18 B-fragment loads ----
    bf16x8 Bf[18];
    #pragma unroll
    for (int i = 0; i < 18; ++i)
        Bf[i] = *(const bf16x8*)(wlin + ((size_t)(iter * 18 + i) * 64 + lane) * 8);

    // ---- phase 2: LDS writes, then barrier ----
    #pragma unroll
    for (int k = 0; k < 6; ++k) {
        int idx = tid + k * 256;
        if (idx < GT_ELEMS) {
            int chunk = idx & 3;
            int p = idx >> 2;
            *(uint4*)((char*)sG + ((size_t)(p * CHL) + chunk * 8) * 2) = gv[k];
        }
    }
    #pragma unroll
    for (int k = 0; k < 5; ++k) {
        int idx = tid + k * 256;
        if (idx < SC_ELEMS) sCur[idx] = cv[k];
    }
    __syncthreads();

    // ---- phase 3: MFMA ----
    f32x16 acc0 = {0,0,0,0,0,0,0,0,0,0,0,0,0,0,0,0};
    f32x16 acc1 = {0,0,0,0,0,0,0,0,0,0,0,0,0,0,0,0};

    #pragma unroll
    for (int ks = 0; ks < 2; ++ks) {
        #pragma unroll
        for (int kw = 0; kw < 3; ++kw) {
            bf16x8 A4[4];
            #pragma unroll
            for (int d = 0; d < 4; ++d) {
                const __bf16* ap = sG + (size_t)((2 * w + d) * HALO_W + xl + kw) * CHL
                                 + ks * 16 + half * 8;
                A4[d] = *(const bf16x8*)ap;
            }
            #pragma unroll
            for (int kh = 0; kh < 3; ++kh) {
                int t = kh * 3 + kw;
                // swapped operands: D[oc][px]; acc0 = output row 2w, acc1 = 2w+1
                acc0 = __builtin_amdgcn_mfma_f32_32x32x16_bf16(Bf[t * 2 + ks], A4[kh],     acc0, 0, 0, 0);
                acc1 = __builtin_amdgcn_mfma_f32_32x32x16_bf16(Bf[t * 2 + ks], A4[kh + 1], acc1, 0, 0, 0);
            }
        }
    }

    // ---- in-wave channel completion ----
    // D layout 32x32: col = lane&31 = pixel x, row(oc) = (r&3)+8*(r>>2)+4*(lane>>5).
    float oth[16];
    #pragma unroll
    for (int r = 0; r < 16; ++r) {
        float send = half ? acc0[r] : acc1[r];
        oth[r] = __shfl_xor(send, 32, 64);
    }

    float v27[CH_];
    #pragma unroll
    for (int c = 0; c < CH_; ++c) {
        int r = (c & 3) + 4 * (c >> 3);
        int hc = (c >> 2) & 1;
        float own = half ? acc1[r] : acc0[r];
        float val = (hc == half) ? own : oth[r];
        int oc = (c < 18) ? (iter * 18 + c) : (54 + iter * NUM_ + (c - 18));
        v27[c] = val + conv_b[oc];     // wave-uniform -> scalar load
    }

    // ---- softmax over aff channels 18..26 ----
    float m = v27[18];
    #pragma unroll
    for (int n = 1; n < 9; ++n) m = fmaxf(m, v27[18 + n]);
    float a[9]; float s = 0.f;
    #pragma unroll
    for (int n = 0; n < 9; ++n) { a[n] = __expf(v27[18 + n] - m); s += a[n]; }
    const float inv_s = 1.f / s;

    // ---- 9-tap bilinear propagation (LDS window, global fallback) ----
    const int x = tileX0 + xl;
    const int y = tileY0 + 2 * w + half;
    float agg = 0.f;
    #pragma unroll
    for (int n = 0; n < 9; ++n) {
        float px = v27[2 * n]     + tap[2 * n]     + (float)x;
        float py = v27[2 * n + 1] + tap[2 * n + 1] + (float)y;
        float x0f = floorf(px), y0f = floorf(py);
        float wx = px - x0f, wy = py - y0f;
        int x0 = (int)x0f, y0 = (int)y0f;
        int lx = x0 - winX0, ly = y0 - winY0;
        float v00, v01, v10, v11;
        if ((unsigned)lx <= (unsigned)(HS_W - 2) && (unsigned)ly <= (unsigned)(HS_H - 2)) {
            int li = ly * HS_W + lx;
            v00 = sCur[li];
            v01 = sCur[li + 1];
            v10 = sCur[li + HS_W];
            v11 = sCur[li + HS_W + 1];
        } else {
            bool vx0 = (x0 >= 0) && (x0 < W_);
            bool vx1 = (x0 + 1 >= 0) && (x0 + 1 < W_);
            bool vy0 = (y0 >= 0) && (y0 < H_);
            bool vy1 = (y0 + 1 >= 0) && (y0 + 1 < H_);
            int cx0 = min(max(x0, 0), W_ - 1), cx1 = min(max(x0 + 1, 0), W_ - 1);
            int cy0 = min(max(y0, 0), H_ - 1), cy1 = min(max(y0 + 1, 0), H_ - 1);
            v00 = 0.f; v01 = 0.f; v10 = 0.f; v11 = 0.f;
            if (vy0) {
                const float* row = cur + (size_t)cy0 * W_;
                if (vx0) v00 = row[cx0];
                if (vx1) v01 = row[cx1];
            }
            if (vy1) {
                const float* row = cur + (size_t)cy1 * W_;
                if (vx0) v10 = row[cx0];
                if (vx1) v11 = row[cx1];
            }
        }
        float val = (1.f - wy) * ((1.f - wx) * v00 + wx * v01)
                  +        wy  * ((1.f - wx) * v10 + wx * v11);
        agg = fmaf(val, a[n] * inv_s, agg);
    }

    const int pix = b * (H_ * W_) + y * W_ + x;
    float c  = confidence[pix];
    float sp = sp_dep[pix];
    float sgn = (sp > 0.f) ? 1.f : ((sp < 0.f) ? -1.f : 0.f);
    float conf = sgn / (1.f + __expf(-c));
    float nc = (1.f - conf) * agg + conf * sp;

    out_cur[pix] = nc;
    if (pred) pred[pix] = nc;
    if (feat) feat[pix] = input[pix];
}

// ---------------------------------------------------------------------------
// Fallback (fp32 direct) if workspace is too small
// ---------------------------------------------------------------------------
__global__ __launch_bounds__(256) void dyspn_iter_fp32(
    const float* __restrict__ guide, const float* __restrict__ conv_w,
    const float* __restrict__ conv_b, const float* __restrict__ tap,
    const float* __restrict__ confidence, const float* __restrict__ sp_dep,
    const float* __restrict__ cur_in, float* __restrict__ out_cur,
    float* __restrict__ pred, float* __restrict__ feat,
    const float* __restrict__ input, int iter)
{
    __shared__ float sg[CH_ * HALO_H * HALO_W];
    const int tid = threadIdx.x;
    const int tileX0 = blockIdx.x * TX;
    const int tileY0 = blockIdx.y * TY;
    const int b = blockIdx.z;
    for (int idx = tid; idx < CH_ * HALO_H * HALO_W; idx += 256) {
        int ic  = idx / (HALO_H * HALO_W);
        int rem = idx % (HALO_H * HALO_W);
        int ly = rem / HALO_W;
        int lx = rem % HALO_W;
        int gy = tileY0 + ly - 1;
        int gx = tileX0 + lx - 1;
        float v = 0.f;
        if (gx >= 0 && gx < W_ && gy >= 0 && gy < H_)
            v = guide[((b * CH_ + ic) * H_ + gy) * W_ + gx];
        sg[idx] = v;
    }
    __syncthreads();
    const int tx = tid % TX;
    const int ty = tid / TX;
    const int x = tileX0 + tx;
    const int y = tileY0 + ty;
    const int oc0 = iter * 18;
    const int oc1 = 54 + iter * NUM_;
    float acc[27];
    #pragma unroll
    for (int j = 0; j < 18; ++j) acc[j] = conv_b[oc0 + j];
    #pragma unroll
    for (int j = 0; j < 9; ++j)  acc[18 + j] = conv_b[oc1 + j];
    for (int ic = 0; ic < CH_; ++ic) {
        float g[9];
        #pragma unroll
        for (int t = 0; t < 9; ++t) {
            int dy = t / 3, dx = t % 3;
            g[t] = sg[ic * (HALO_H * HALO_W) + (ty + dy) * HALO_W + (tx + dx)];
        }
        #pragma unroll
        for (int j = 0; j < 18; ++j) {
            const float* wp = conv_w + ((oc0 + j) * CH_ + ic) * 9;
            #pragma unroll
            for (int t = 0; t < 9; ++t) acc[j] = fmaf(wp[t], g[t], acc[j]);
        }
        #pragma unroll
        for (int j = 0; j < 9; ++j) {
            const float* wp = conv_w + ((oc1 + j) * CH_ + ic) * 9;
            #pragma unroll
            for (int t = 0; t < 9; ++t) acc[18 + j] = fmaf(wp[t], g[t], acc[18 + j]);
        }
    }
    float m = acc[18];
    #pragma unroll
    for (int n = 1; n < 9; ++n) m = fmaxf(m, acc[18 + n]);
    float a[9]; float s = 0.f;
    #pragma unroll
    for (int n = 0; n < 9; ++n) { a[n] = __expf(acc[18 + n] - m); s += a[n]; }
    const float inv_s = 1.f / s;
    const float* cur = cur_in + b * (H_ * W_);
    float agg = 0.f;
    #pragma unroll
    for (int n = 0; n < 9; ++n) {
        float px = acc[2 * n]     + tap[2 * n]     + (float)x;
        float py = acc[2 * n + 1] + tap[2 * n + 1] + (float)y;
        float x0f = floorf(px), y0f = floorf(py);
        float wx = px - x0f, wy = py - y0f;
        int x0 = (int)x0f, y0 = (int)y0f;
        bool vx0 = (x0 >= 0) && (x0 < W_);
        bool vx1 = (x0 + 1 >= 0) && (x0 + 1 < W_);
        bool vy0 = (y0 >= 0) && (y0 < H_);
        bool vy1 = (y0 + 1 >= 0) && (y0 + 1 < H_);
        int cx0 = min(max(x0, 0), W_ - 1), cx1 = min(max(x0 + 1, 0), W_ - 1);
        int cy0 = min(max(y0, 0), H_ - 1), cy1 = min(max(y0 + 1, 0), H_ - 1);
        float v00 = 0.f, v01 = 0.f, v10 = 0.f, v11 = 0.f;
        if (vy0) {
            const float* row = cur + cy0 * W_;
            if (vx0) v00 = row[cx0];
            if (vx1) v01 = row[cx1];
        }
        if (vy1) {
            const float* row = cur + cy1 * W_;
            if (vx0) v10 = row[cx0];
            if (vx1) v11 = row[cx1];
        }
        float val = (1.f - wy) * ((1.f - wx) * v00 + wx * v01)
                  +        wy  * ((1.f - wx) * v10 + wx * v11);
        agg = fmaf(val, a[n] * inv_s, agg);
    }
    const int pix = b * (H_ * W_) + y * W_ + x;
    float c  = confidence[pix];
    float sp = sp_dep[pix];
    float sgn = (sp > 0.f) ? 1.f : ((sp < 0.f) ? -1.f : 0.f);
    float conf = sgn / (1.f + __expf(-c));
    float nc = (1.f - conf) * agg + conf * sp;
    out_cur[pix] = nc;
    if (pred) pred[pix] = nc;
    if (feat) feat[pix] = input[pix];
}

extern "C" void kernel_launch(void* const* d_in, const int* in_sizes, int n_in,
                              void* d_out, int out_size, void* d_ws, size_t ws_size,
                              hipStream_t stream) {
    (void)in_sizes; (void)n_in; (void)out_size;
    const float* input      = (const float*)d_in[0];
    const float* guide      = (const float*)d_in[1];
    const float* sp_dep     = (const float*)d_in[2];
    const float* confidence = (const float*)d_in[3];
    const float* conv_w     = (const float*)d_in[4];
    const float* conv_b     = (const float*)d_in[5];
    const float* tap        = (const float*)d_in[6];

    float* out   = (float*)d_out;
    const int P  = PIX_;
    float* pred  = out;
    float* feat  = out + P;
    float* inter = out + 2 * P;

    const size_t gt_bytes   = (size_t)PIX_ * CHP * 2;          // 37,355,520
    const size_t wlin_bytes = (size_t)3 * 9 * 2 * 64 * 8 * 2;  // 55,296

    if (ws_size >= gt_bytes + wlin_bytes) {
        __bf16* gt   = (__bf16*)d_ws;
        __bf16* wlin = (__bf16*)((char*)d_ws + gt_bytes);

        transpose_guide<<<(PIX_ + 255) / 256, 256, 0, stream>>>(guide, gt);
        prep_weights<<<(3 * 9 * 2 * 64 + 255) / 256, 256, 0, stream>>>(conv_w, wlin);

        for (int i = 0; i < 3; ++i) {
            const float* cur = (i == 0) ? input : (inter + (i - 1) * P);
            dyspn_iter_v9<<<dim3(NBLK), dim3(256), 0, stream>>>(
                gt, wlin, conv_b, tap, confidence, sp_dep,
                cur, inter + i * P,
                (i == 2) ? pred : nullptr,
                (i == 0) ? feat : nullptr,
                input, i);
        }
    } else {
        dim3 grid(W_ / TX, H_ / TY, B_);
        for (int i = 0; i < 3; ++i) {
            const float* cur = (i == 0) ? input : (inter + (i - 1) * P);
            dyspn_iter_fp32<<<grid, 256, 0, stream>>>(
                guide, conv_w, conv_b, tap, confidence, sp_dep,
                cur, inter + i * P,
                (i == 2) ? pred : nullptr,
                (i == 0) ? feat : nullptr,
                input, i);
        }
    }
}